// Round 10
// baseline (261.856 us; speedup 1.0000x reference)
//
#include <hip/hip_runtime.h>

// incidence_matrix_learn on MI355X — round 10.
// Round-9 post-mortem: (1) ~15 µs/launch inter-dispatch overhead dominates
// (6 launches ≈ 90 µs of 249.5); (2) lse tournament blocks are imbalanced
// (6-tile vs 3-tile makespan, MfmaUtil 10.5%, occupancy 10%).
// Fixes: (a) 3 launches total — prep also zeros seG/posG/acc/done; reduce
// rebuilds the label histogram itself (cnt folded in) and finishes the loss
// in its LAST block (threadfence + done counter, acc read via atomicAdd(p,0));
// (b) lse flattened to one block per (batch, unordered tile-pair): 4864
// uniform blocks, idx = p*64 + b so XCD = b%8 (L2 locality preserved).
// Validated algebra (rounds 1-9, absmax 0.0): top-k no-op; P via labels;
// fixed-shift-10 LSE; bf16 nhat; cnt = label-histogram - 1; symmetric pairs.

#define DDIM 512
#define BATCH 64

typedef __attribute__((ext_vector_type(8))) short short8;
typedef __attribute__((ext_vector_type(4))) float f32x4;

__device__ __forceinline__ unsigned short f2bf(float f) {
  unsigned int u = __float_as_uint(f);
  u += 0x7fffu + ((u >> 16) & 1u);   // RNE
  return (unsigned short)(u >> 16);
}

__device__ __forceinline__ void async16(const void* g, void* l) {
  __builtin_amdgcn_global_load_lds(
      (const __attribute__((address_space(1))) unsigned int*)g,
      (__attribute__((address_space(3))) unsigned int*)l, 16, 0, 0);
}

// Fused prep kernel, 256 threads. Blocks [0,1024): adj (both scales).
// [1024, 17408): normalize, one WAVE per node row. [17408, 17472): zero
// seG/posG (131072 floats) + acc + done.
__global__ __launch_bounds__(256) void prep_kernel(
    const float* __restrict__ enod0, const float* __restrict__ ehy0,
    const float* __restrict__ enod1, const float* __restrict__ ehy1,
    float* __restrict__ adj0, float* __restrict__ adj1,
    int* __restrict__ labels0, int* __restrict__ labels1,
    const float* __restrict__ x0, const float* __restrict__ w0,
    const float* __restrict__ x1, const float* __restrict__ w1,
    unsigned short* __restrict__ nhat0, unsigned short* __restrict__ nhat1,
    float* __restrict__ fz, float* __restrict__ acc, int* __restrict__ done) {
  const int t = threadIdx.x;
  if (blockIdx.x < 1024) {
    // ---- adj path ----
    const bool s0 = blockIdx.x < 640;
    const int n = s0 ? blockIdx.x : blockIdx.x - 640;
    const int H = s0 ? 128 : 64;
    const float* enod = s0 ? enod0 : enod1;
    const float* ehy = s0 ? ehy0 : ehy1;
    float* out_adj = s0 ? adj0 : adj1;
    int* labels = s0 ? labels0 : labels1;
    __shared__ float erow[DDIM];
    __shared__ float red[128];
    __shared__ int lab;
    if (t < 128) ((float4*)erow)[t] = ((const float4*)(enod + (size_t)n * DDIM))[t];
    if (t == 0) lab = -1;
    __syncthreads();
    float v = 0.f;
    if (t < H) {
      const float4* hr = (const float4*)(ehy + (size_t)t * DDIM);
      float a = 0.f;
      #pragma unroll 8
      for (int d = 0; d < DDIM / 4; ++d) {
        float4 h = hr[d];
        float4 e = ((const float4*)erow)[d];
        a = fmaf(h.x, e.x, a); a = fmaf(h.y, e.y, a);
        a = fmaf(h.z, e.z, a); a = fmaf(h.w, e.w, a);
      }
      v = fmaxf(0.f, 3.0f * a);
    }
    if (t < 128) red[t] = v;
    __syncthreads();
    for (int s = 64; s > 0; s >>= 1) {
      if (t < s) red[t] = fmaxf(red[t], red[t + s]);
      __syncthreads();
    }
    const float mx = red[0];
    __syncthreads();
    const float e = (t < H) ? __expf(v - mx) : 0.f;
    if (t < 128) red[t] = e;
    __syncthreads();
    for (int s = 64; s > 0; s >>= 1) {
      if (t < s) red[t] += red[t + s];
      __syncthreads();
    }
    const float sum = red[0];
    if (t < H) {
      const float adj = e / sum;
      const float bin = (adj > 0.5f) ? 1.0f : 0.0f;
      out_adj[(size_t)n * H + t] = bin;
      if (bin > 0.f) lab = t;
    }
    __syncthreads();
    if (t == 0) labels[n] = lab;
  } else if (blockIdx.x < 17408) {
    // ---- normalize path: wave per row ----
    const int wave = t >> 6;
    const int lane = t & 63;
    const int g = (blockIdx.x - 1024) * 4 + wave;   // global row id, < 65536
    const bool s0 = g < BATCH * 640;
    const int gg = s0 ? g : g - BATCH * 640;
    const int N = s0 ? 640 : 384;
    const int L = s0 ? 512 : 256;
    const float* x = s0 ? x0 : x1;
    const float* w = s0 ? w0 : w1;
    unsigned short* nhat = s0 ? nhat0 : nhat1;
    const int b = gg / N;
    const int n = gg - b * N;
    const float* src = (n < L) ? (x + ((size_t)b * L + n) * DDIM)
                               : (w + (size_t)(n - L) * DDIM);
    const float4* rowp = (const float4*)src;
    const float4 v0 = rowp[lane];
    const float4 v1 = rowp[lane + 64];
    float ss = v0.x * v0.x + v0.y * v0.y + v0.z * v0.z + v0.w * v0.w +
               v1.x * v1.x + v1.y * v1.y + v1.z * v1.z + v1.w * v1.w;
    #pragma unroll
    for (int off = 32; off > 0; off >>= 1) ss += __shfl_xor(ss, off);
    const float rinv = 1.0f / fmaxf(sqrtf(ss), 1e-12f);
    ushort4 o0, o1;
    o0.x = f2bf(v0.x * rinv); o0.y = f2bf(v0.y * rinv);
    o0.z = f2bf(v0.z * rinv); o0.w = f2bf(v0.w * rinv);
    o1.x = f2bf(v1.x * rinv); o1.y = f2bf(v1.y * rinv);
    o1.z = f2bf(v1.z * rinv); o1.w = f2bf(v1.w * rinv);
    ushort4* op = (ushort4*)(nhat + ((size_t)b * N + n) * DDIM);
    op[lane] = o0;
    op[lane + 64] = o1;
  } else {
    // ---- zero path: 64 blocks x 512 float4 = 131072 floats ----
    const int zb = blockIdx.x - 17408;
    float4* dst = (float4*)fz;
    const float4 z = {0.f, 0.f, 0.f, 0.f};
    dst[zb * 512 + t] = z;
    dst[zb * 512 + t + 256] = z;
    if (zb == 0 && t == 0) { acc[0] = 0.f; acc[1] = 0.f; *done = 0; }
  }
}

// Flattened symmetric-pair MFMA lse kernel: one block (2 waves, 128 thr) per
// (batch, unordered tile-pair). scale0: 55 pairs x 64 b = 3520 blocks;
// scale1: 21 x 64 = 1344. idx = p*64 + b -> XCD = b%8. Each block: one 64x64
// tile (n-tile i, m-tile j, i<=j), K=512 in 4 chunks, B double-buffered
// frag-order LDS, prefetch 1 chunk ahead. Row-side always; col-side iff i!=j.
__global__ __launch_bounds__(128, 1) void lse_kernel(
    const unsigned short* __restrict__ nhat0, const int* __restrict__ labels0,
    const unsigned short* __restrict__ nhat1, const int* __restrict__ labels1,
    float* __restrict__ seG0, float* __restrict__ posG0,
    float* __restrict__ seG1, float* __restrict__ posG1) {
  __shared__ short8 Bbuf[2][1024];   // 2 x 16 KB, frag-order
  __shared__ int labS[640];
  const int tid = threadIdx.x;
  const bool s0 = blockIdx.x < 3520;
  const int idx = s0 ? blockIdx.x : blockIdx.x - 3520;
  const int N = s0 ? 640 : 384;
  const int T = s0 ? 10 : 6;
  const unsigned short* nhat = s0 ? nhat0 : nhat1;
  const int* labels = s0 ? labels0 : labels1;
  float* seG = s0 ? seG0 : seG1;
  float* posG = s0 ? posG0 : posG1;
  const int b = idx & 63;       // XCD swizzle: batch fixes XCD residue
  int p = idx >> 6;             // triangular pair index -> (i, j), i <= j
  int i = 0;
  while (p >= T - i) { p -= T - i; ++i; }
  const int j = i + p;
  const int n0 = i * 64;
  const int m0 = j * 64;
  const int wave = tid >> 6;    // 0..1
  const int lane = tid & 63;
  const int lrow = lane & 15;   // A-row within 16 / B-col / C-col
  const int lq = lane >> 4;     // k-chunk selector / C row group
  for (int t = tid; t < N; t += 128) labS[t] = labels[t];

  const size_t base = (size_t)b * N * DDIM;
  const int rw0 = n0 + wave * 32;   // wave owns rows rw0 .. rw0+31
  const unsigned short* Ap0 = nhat + base + (size_t)(rw0 + lrow) * DDIM + lq * 8;
  const unsigned short* Ap1 = nhat + base + (size_t)(rw0 + 16 + lrow) * DDIM + lq * 8;
  short8 a0[16], a1[16];
  #pragma unroll
  for (int ks = 0; ks < 16; ++ks) {
    a0[ks] = *(const short8*)(Ap0 + ks * 32);
    a1[ks] = *(const short8*)(Ap1 + ks * 32);
  }

  // stage chunk 0: this wave's 8 frags f = wave*8 .. +7 of the m-tile
  const int f0 = wave * 8;
  #pragma unroll
  for (int fi = 0; fi < 8; ++fi) {
    const int f = f0 + fi;
    const int jf = f >> 2, ks = f & 3;
    const unsigned short* g = nhat + base +
        (size_t)(m0 + jf * 16 + lrow) * DDIM + ks * 32 + lq * 8;
    async16(g, &Bbuf[0][f * 64]);
  }
  __syncthreads();   // drains staging (vmcnt) + labS writes

  int labn[2][4];
  #pragma unroll
  for (int s = 0; s < 2; ++s)
    #pragma unroll
    for (int r = 0; r < 4; ++r) labn[s][r] = labS[rw0 + s * 16 + lq * 4 + r];

  f32x4 acc[4][2];
  #pragma unroll
  for (int jj = 0; jj < 4; ++jj) {
    acc[jj][0] = (f32x4){0.f, 0.f, 0.f, 0.f};
    acc[jj][1] = (f32x4){0.f, 0.f, 0.f, 0.f};
  }
  #pragma unroll
  for (int kc = 0; kc < 4; ++kc) {
    if (kc < 3) {   // prefetch chunk kc+1 into buffer parity (kc+1)&1
      short8* dst = &Bbuf[(kc + 1) & 1][0];
      #pragma unroll
      for (int fi = 0; fi < 8; ++fi) {
        const int f = f0 + fi;
        const int jf = f >> 2, ks = f & 3;
        const unsigned short* g = nhat + base +
            (size_t)(m0 + jf * 16 + lrow) * DDIM +
            (kc + 1) * 128 + ks * 32 + lq * 8;
        async16(g, dst + f * 64);
      }
    }
    // compute chunk kc from Bbuf[kc&1]; all register indices compile-time
    const short8* bb = &Bbuf[kc & 1][0];
    #pragma unroll
    for (int ks = 0; ks < 4; ++ks) {
      const short8 b0 = bb[(0 + ks) * 64 + lane];
      const short8 b1 = bb[(4 + ks) * 64 + lane];
      const short8 b2 = bb[(8 + ks) * 64 + lane];
      const short8 b3 = bb[(12 + ks) * 64 + lane];
      const short8 av0 = a0[kc * 4 + ks];
      const short8 av1 = a1[kc * 4 + ks];
      acc[0][0] = __builtin_amdgcn_mfma_f32_16x16x32_bf16(av0, b0, acc[0][0], 0, 0, 0);
      acc[0][1] = __builtin_amdgcn_mfma_f32_16x16x32_bf16(av1, b0, acc[0][1], 0, 0, 0);
      acc[1][0] = __builtin_amdgcn_mfma_f32_16x16x32_bf16(av0, b1, acc[1][0], 0, 0, 0);
      acc[1][1] = __builtin_amdgcn_mfma_f32_16x16x32_bf16(av1, b1, acc[1][1], 0, 0, 0);
      acc[2][0] = __builtin_amdgcn_mfma_f32_16x16x32_bf16(av0, b2, acc[2][0], 0, 0, 0);
      acc[2][1] = __builtin_amdgcn_mfma_f32_16x16x32_bf16(av1, b2, acc[2][1], 0, 0, 0);
      acc[3][0] = __builtin_amdgcn_mfma_f32_16x16x32_bf16(av0, b3, acc[3][0], 0, 0, 0);
      acc[3][1] = __builtin_amdgcn_mfma_f32_16x16x32_bf16(av1, b3, acc[3][1], 0, 0, 0);
    }
    if (kc < 3) __syncthreads();   // staging for kc+1 drained; swap safe
  }

  // epilogue: row-side registers + col-side partials
  float se[2][4] = {{0.f, 0.f, 0.f, 0.f}, {0.f, 0.f, 0.f, 0.f}};
  float pos[2][4] = {{0.f, 0.f, 0.f, 0.f}, {0.f, 0.f, 0.f, 0.f}};
  float colE[4] = {0.f, 0.f, 0.f, 0.f};
  float colP[4] = {0.f, 0.f, 0.f, 0.f};
  #pragma unroll
  for (int jj = 0; jj < 4; ++jj) {
    const int m = m0 + jj * 16 + lrow;
    const int labm = labS[m];
    #pragma unroll
    for (int s = 0; s < 2; ++s) {
      const int row0 = rw0 + s * 16 + lq * 4;
      #pragma unroll
      for (int r = 0; r < 4; ++r) {
        const float sim = acc[jj][s][r] * 10.0f;   // 1/TAU
        const float e = __expf(sim - 10.0f);       // fixed shift (diag max)
        const bool match =
            labn[s][r] >= 0 && labm == labn[s][r] && m != row0 + r;
        const float pv = match ? sim : 0.f;
        se[s][r] += e;
        pos[s][r] += pv;
        colE[jj] += e;
        colP[jj] += pv;
      }
    }
  }
  if (i != j) {   // col-side: symmetric contribution to rows m (off-diag only)
    #pragma unroll
    for (int jj = 0; jj < 4; ++jj) {
      float ce = colE[jj], cp = colP[jj];
      ce += __shfl_xor(ce, 16); ce += __shfl_xor(ce, 32);
      cp += __shfl_xor(cp, 16); cp += __shfl_xor(cp, 32);
      if (lq == 0) {
        const int m = m0 + jj * 16 + lrow;
        atomicAdd(&seG[b * N + m], ce);
        atomicAdd(&posG[b * N + m], cp);
      }
    }
  }
  // row-side flush: reduce across the 16 col-lanes of each row group
  #pragma unroll
  for (int off = 1; off <= 8; off <<= 1) {
    #pragma unroll
    for (int s = 0; s < 2; ++s)
      #pragma unroll
      for (int r = 0; r < 4; ++r) {
        se[s][r] += __shfl_xor(se[s][r], off);
        pos[s][r] += __shfl_xor(pos[s][r], off);
      }
  }
  if (lrow == 0) {
    #pragma unroll
    for (int s = 0; s < 2; ++s)
      #pragma unroll
      for (int r = 0; r < 4; ++r) {
        const int row = rw0 + s * 16 + lq * 4 + r;
        atomicAdd(&seG[b * N + row], se[s][r]);
        atomicAdd(&posG[b * N + row], pos[s][r]);
      }
  }
}

// 256 blocks x 256 thr over 65536 rows (blocks [0,160): scale0, [160,256):
// scale1). Each block rebuilds the label histogram (cnt folded in), computes
// per-row loss, block-reduces, atomicAdds into acc[scale]. The LAST block
// (done counter) rebuilds both hists for valid0/1, reads acc coherently via
// atomicAdd(p, 0), writes the final loss (final kernel folded in).
__global__ __launch_bounds__(256) void reduce_kernel(
    const float* __restrict__ seG0, const float* __restrict__ posG0,
    const float* __restrict__ seG1, const float* __restrict__ posG1,
    const int* __restrict__ labels0, const int* __restrict__ labels1,
    float* __restrict__ acc, int* __restrict__ done,
    float* __restrict__ out_loss) {
  __shared__ int lab[640];
  __shared__ int hist[128];
  __shared__ float bsum[4];
  __shared__ int flag;
  const int t = threadIdx.x;
  const bool s0 = blockIdx.x < 160;
  const int N = s0 ? 640 : 384;
  const int H = s0 ? 128 : 64;
  const int* labels = s0 ? labels0 : labels1;
  if (t < H) hist[t] = 0;
  for (int n = t; n < N; n += 256) lab[n] = labels[n];
  __syncthreads();
  for (int n = t; n < N; n += 256)
    if (lab[n] >= 0) atomicAdd(&hist[lab[n]], 1);
  __syncthreads();
  const int row = blockIdx.x * 256 + t;
  float v = 0.f;
  if (s0) {
    const int n = row % 640;
    const int c = (lab[n] >= 0) ? hist[lab[n]] - 1 : 0;
    if (c > 0) v = (10.0f + logf(seG0[row])) - posG0[row] / (float)c;
  } else {
    const int k = row - BATCH * 640;
    const int n = k % 384;
    const int c = (lab[n] >= 0) ? hist[lab[n]] - 1 : 0;
    if (c > 0) v = (10.0f + logf(seG1[k])) - posG1[k] / (float)c;
  }
  #pragma unroll
  for (int off = 32; off > 0; off >>= 1) v += __shfl_xor(v, off);
  if ((t & 63) == 0) bsum[t >> 6] = v;
  __syncthreads();
  if (t == 0) {
    atomicAdd(&acc[s0 ? 0 : 1], bsum[0] + bsum[1] + bsum[2] + bsum[3]);
    __threadfence();
    const int old = atomicAdd(done, 1);
    flag = (old == (int)gridDim.x - 1) ? 1 : 0;
  }
  __syncthreads();
  if (flag) {
    // last block: valid counts + final loss
    __shared__ int h0[128];
    __shared__ int h1[64];
    __shared__ int vcnt[2];
    if (t < 128) h0[t] = 0;
    if (t < 64) h1[t] = 0;
    if (t < 2) vcnt[t] = 0;
    __syncthreads();
    for (int n = t; n < 640; n += 256) {
      const int l = labels0[n];
      if (l >= 0) atomicAdd(&h0[l], 1);
    }
    for (int n = t; n < 384; n += 256) {
      const int l = labels1[n];
      if (l >= 0) atomicAdd(&h1[l], 1);
    }
    __syncthreads();
    int c0 = 0, c1 = 0;
    for (int n = t; n < 640; n += 256) {
      const int l = labels0[n];
      if (l >= 0 && h0[l] >= 2) ++c0;
    }
    for (int n = t; n < 384; n += 256) {
      const int l = labels1[n];
      if (l >= 0 && h1[l] >= 2) ++c1;
    }
    if (c0 > 0) atomicAdd(&vcnt[0], c0);
    if (c1 > 0) atomicAdd(&vcnt[1], c1);
    __syncthreads();
    if (t == 0) {
      const float a0 = atomicAdd(&acc[0], 0.0f);   // coherent read
      const float a1 = atomicAdd(&acc[1], 0.0f);
      float l = 0.f;
      if (vcnt[0] > 0) l += a0 / (float)(BATCH * vcnt[0]);
      if (vcnt[1] > 0) l += a1 / (float)(BATCH * vcnt[1]);
      *out_loss = l;
    }
  }
}

extern "C" void kernel_launch(void* const* d_in, const int* in_sizes, int n_in,
                              void* d_out, int out_size, void* d_ws,
                              size_t ws_size, hipStream_t stream) {
  const float* x0 = (const float*)d_in[0];
  const float* x1 = (const float*)d_in[1];
  const float* w0 = (const float*)d_in[2];
  const float* w1 = (const float*)d_in[3];
  const float* ehy0 = (const float*)d_in[4];
  const float* ehy1 = (const float*)d_in[5];
  const float* enod0 = (const float*)d_in[6];
  const float* enod1 = (const float*)d_in[7];

  float* out = (float*)d_out;
  float* adj0 = out;                       // 640*128
  float* adj1 = out + 640 * 128;           // 384*64
  float* lossp = out + 640 * 128 + 384 * 64;

  unsigned short* nhat0 = (unsigned short*)d_ws;
  unsigned short* nhat1 = nhat0 + (size_t)BATCH * 640 * DDIM;
  int* labels0 = (int*)(nhat1 + (size_t)BATCH * 384 * DDIM);
  int* labels1 = labels0 + 640;
  float* seG0 = (float*)(labels1 + 384);   // zeroed region: 131072 floats
  float* posG0 = seG0 + BATCH * 640;
  float* seG1 = posG0 + BATCH * 640;
  float* posG1 = seG1 + BATCH * 384;
  float* acc = posG1 + BATCH * 384;        // 2 floats
  int* done = (int*)(acc + 2);             // 1 int

  prep_kernel<<<17472, 256, 0, stream>>>(
      enod0, ehy0, enod1, ehy1, adj0, adj1, labels0, labels1,
      x0, w0, x1, w1, nhat0, nhat1, seG0, acc, done);
  lse_kernel<<<4864, 128, 0, stream>>>(nhat0, labels0, nhat1, labels1,
                                       seG0, posG0, seG1, posG1);
  reduce_kernel<<<256, 256, 0, stream>>>(seG0, posG0, seG1, posG1,
                                         labels0, labels1, acc, done, lossp);
}